// Round 6
// baseline (89.171 us; speedup 1.0000x reference)
//
#include <hip/hip_runtime.h>

// SKANLinear: y[b,o] = sum_{i=0}^{IN} weight[o,i] * sin(w[o,i] * x_ext[b,i])
// x_ext[b,IN] = 1.0. B=2048, IN=256, OUT=256. f32.
//
// R6: back-solved cycle model across R1-R5 says v_sin_f32 is ~36-38
// cyc/wave64 (~1/16 rate) on gfx950, making every memory-path change
// neutral. Replace it with a full-rate polynomial:
//   xs pre-scaled by 1/(2pi) -> arg = w*xs is in revolutions
//   f = arg - rint(arg) in [-0.5,0.5]   (v_rndne_f32)
//   sin(2*pi*f) = f * P(f^2), P = deg-13 odd Taylor, |err| <= 2.2e-5
//   g*sin = (f*g) * P  -> 12 full-rate VALU instrs = 24 cyc/elem (was ~42)
// Skeleton = R5: lane = b, wave = uniform o-pair (weights via scalar pipe),
// x chunk through XOR-swizzled LDS float4, per-lane full sums, no shuffles.

#define IN_DIM 256
#define OUT_DIM 256
#define LDW 257
#define CH 32             // i-chunk width
#define INV_2PI 0.15915494309189535f

// Taylor coefficients for sin(2*pi*f) = f*(C1 + u*(C3 + ...)), u = f^2
#define C1   6.2831853071795865f
#define C3  -41.341702240399755f
#define C5   81.605249276075040f
#define C7  -76.705859753061360f
#define C9   42.058693944897650f
#define C11 -15.094642576059076f
#define C13  3.8199525848482821f

__device__ __forceinline__ float sin2pi_poly(float arg) {
    const float f = arg - __builtin_rintf(arg);   // v_rndne_f32
    const float u = f * f;
    float p = C13;
    p = fmaf(p, u, C11);
    p = fmaf(p, u, C9);
    p = fmaf(p, u, C7);
    p = fmaf(p, u, C5);
    p = fmaf(p, u, C3);
    p = fmaf(p, u, C1);
    return f * p;   // callers that can fold the f-mul should use f,p directly
}

__global__ __launch_bounds__(256, 4)
void skan_kernel(const float* __restrict__ x,      // [2048][256]
                 const float* __restrict__ weight, // [256][257]
                 const float* __restrict__ wfreq,  // [256][257]
                 float* __restrict__ y)            // [2048][256]
{
    __shared__ float4 lx4[64 * 8];   // one 64b x 32i chunk, swizzled, 8 KB

    const int t  = threadIdx.x;
    const int l  = t & 63;                                   // lane = local b
    const int wv = __builtin_amdgcn_readfirstlane(t >> 6);   // wave id, uniform

    const int obase = (blockIdx.x & 31) * 8;
    const int b0    = (blockIdx.x >> 5) * 64;

    const int o0 = obase + wv * 2;
    const int o1 = o0 + 1;
    const float* __restrict__ w0r = wfreq  + o0 * LDW;  // uniform -> s_load
    const float* __restrict__ g0r = weight + o0 * LDW;
    const float* __restrict__ w1r = wfreq  + o1 * LDW;
    const float* __restrict__ g1r = weight + o1 * LDW;

    // bias column (i=256, x_ext=1): each lane owns full (b,o) sums.
    float acc0 = g0r[IN_DIM] * sin2pi_poly(w0r[IN_DIM] * INV_2PI);
    float acc1 = g1r[IN_DIM] * sin2pi_poly(w1r[IN_DIM] * INV_2PI);

    // stage chunk ic: 512 float4 by 256 threads (2 each), coalesced reads,
    // swizzled 16B-aligned LDS writes, pre-scaled by 1/(2pi).
    auto stage = [&](int ic) {
#pragma unroll
        for (int k = 0; k < 2; ++k) {
            const int f  = t + k * 256;
            const int r  = f >> 3;       // local b row
            const int c4 = f & 7;        // float4 block within chunk
            float4 v = *(const float4*)(x + (b0 + r) * IN_DIM + ic * CH + c4 * 4);
            v.x *= INV_2PI; v.y *= INV_2PI; v.z *= INV_2PI; v.w *= INV_2PI;
            lx4[r * 8 + (c4 ^ (r & 7))] = v;
        }
    };

    stage(0);

    for (int ic = 0; ic < 8; ++ic) {
        __syncthreads();

        // readback my b-row: 8 x ds_read_b128, bank-even via swizzle
        float xs[CH];
#pragma unroll
        for (int c4 = 0; c4 < 8; ++c4) {
            const float4 v = lx4[l * 8 + (c4 ^ (l & 7))];
            xs[c4 * 4 + 0] = v.x; xs[c4 * 4 + 1] = v.y;
            xs[c4 * 4 + 2] = v.z; xs[c4 * 4 + 3] = v.w;
        }

        __syncthreads();

        if (ic < 7) stage(ic + 1);   // overlap staging with compute

        // pure full-rate VALU inner: w/g wave-uniform (SGPR operands).
        const int ib = ic * CH;
#pragma unroll
        for (int j = 0; j < CH; ++j) {
            const float xv = xs[j];
            {
                const float arg = w0r[ib + j] * xv;
                const float f = arg - __builtin_rintf(arg);
                const float u = f * f;
                float p = C13;
                p = fmaf(p, u, C11); p = fmaf(p, u, C9);
                p = fmaf(p, u, C7);  p = fmaf(p, u, C5);
                p = fmaf(p, u, C3);  p = fmaf(p, u, C1);
                acc0 = fmaf(f * g0r[ib + j], p, acc0);   // g*f*P
            }
            {
                const float arg = w1r[ib + j] * xv;
                const float f = arg - __builtin_rintf(arg);
                const float u = f * f;
                float p = C13;
                p = fmaf(p, u, C11); p = fmaf(p, u, C9);
                p = fmaf(p, u, C7);  p = fmaf(p, u, C5);
                p = fmaf(p, u, C3);  p = fmaf(p, u, C1);
                acc1 = fmaf(f * g1r[ib + j], p, acc1);
            }
        }
    }

    y[(b0 + l) * OUT_DIM + o0] = acc0;
    y[(b0 + l) * OUT_DIM + o1] = acc1;
}

extern "C" void kernel_launch(void* const* d_in, const int* in_sizes, int n_in,
                              void* d_out, int out_size, void* d_ws, size_t ws_size,
                              hipStream_t stream) {
    const float* x      = (const float*)d_in[0];
    const float* weight = (const float*)d_in[1];
    const float* wfreq  = (const float*)d_in[2];
    float* y            = (float*)d_out;

    const int B = in_sizes[0] / IN_DIM;            // 2048
    const int grid = (B / 64) * (OUT_DIM / 8);     // 32 * 32 = 1024

    skan_kernel<<<grid, 256, 0, stream>>>(x, weight, wfreq, y);
}

// Round 7
// 87.138 us; speedup vs baseline: 1.0233x; 1.0233x over previous
//
#include <hip/hip_runtime.h>

// SKANLinear: y[b,o] = sum_{i=0}^{IN} weight[o,i] * sin(w[o,i] * x_ext[b,i])
// x_ext[b,IN] = 1.0. B=2048, IN=256, OUT=256. f32.
//
// R7: R6 post-mortem shows v_sin runs on the separate TRANS pipe (R2/R4/R5
// trans-bound, VALU idle) while the R6 polynomial is pure VALU (R6 regressed
// by ~ the poly's issue cost). So split the work across BOTH pipes:
//   o0 path: arg = w*xs (VALU) ; v_sin (TRANS) ; fma (VALU)      -> 2 VALU + 1 trans
//   o1 path: deg-13 odd Taylor of sin(2*pi*f), f = arg - rne(arg)
//            via the 1.5*2^23 magic-add round (all full-rate VALU) -> 13 VALU
// Per wave-j: 30 VALU cyc + 1 trans op; pipes overlap across 4 waves/SIMD.
// VALU floor 12.8 us; trans floor 3.4-15.4 us depending on v_sin rate.
// Skeleton = R4/R5 (best measured): lane = b, wave = uniform o-pair
// (weights via scalar pipe), x chunk via XOR-swizzled LDS float4 staged
// pre-scaled by 1/(2pi), per-lane full sums, no shuffles.

#define IN_DIM 256
#define OUT_DIM 256
#define LDW 257
#define CH 32             // i-chunk width
#define INV_2PI 0.15915494309189535f
#define RND_MAGIC 12582912.0f   // 1.5*2^23: (a+M)-M = round-to-nearest-even(a), |a|<2^22

// sin(2*pi*f) = f*(C1 + u*(C3 + u*(C5 + ... ))), u = f^2, f in [-0.5,0.5]
// deg-13 Taylor, |err| <= 2.2e-5
#define C1   6.2831853071795865f
#define C3  -41.341702240399755f
#define C5   81.605249276075040f
#define C7  -76.705859753061360f
#define C9   42.058693944897650f
#define C11 -15.094642576059076f
#define C13  3.8199525848482821f

__global__ __launch_bounds__(256, 4)
void skan_kernel(const float* __restrict__ x,      // [2048][256]
                 const float* __restrict__ weight, // [256][257]
                 const float* __restrict__ wfreq,  // [256][257]
                 float* __restrict__ y)            // [2048][256]
{
    __shared__ float4 lx4[64 * 8];   // one 64b x 32i chunk, swizzled, 8 KB

    const int t  = threadIdx.x;
    const int l  = t & 63;                                   // lane = local b
    const int wv = __builtin_amdgcn_readfirstlane(t >> 6);   // wave id, uniform

    const int obase = (blockIdx.x & 31) * 8;
    const int b0    = (blockIdx.x >> 5) * 64;

    const int o0 = obase + wv * 2;
    const int o1 = o0 + 1;
    const float* __restrict__ w0r = wfreq  + o0 * LDW;  // uniform -> s_load
    const float* __restrict__ g0r = weight + o0 * LDW;
    const float* __restrict__ w1r = wfreq  + o1 * LDW;
    const float* __restrict__ g1r = weight + o1 * LDW;

    // bias column (i=256, x_ext=1): each lane owns full (b,o) sums.
    float acc0 = g0r[IN_DIM] * __builtin_amdgcn_sinf(w0r[IN_DIM] * INV_2PI);
    float acc1 = g1r[IN_DIM] * __builtin_amdgcn_sinf(w1r[IN_DIM] * INV_2PI);

    // stage chunk ic: 512 float4 by 256 threads (2 each), coalesced reads,
    // swizzled 16B-aligned LDS writes, pre-scaled by 1/(2pi).
    auto stage = [&](int ic) {
#pragma unroll
        for (int k = 0; k < 2; ++k) {
            const int f  = t + k * 256;
            const int r  = f >> 3;       // local b row
            const int c4 = f & 7;        // float4 block within chunk
            float4 v = *(const float4*)(x + (b0 + r) * IN_DIM + ic * CH + c4 * 4);
            v.x *= INV_2PI; v.y *= INV_2PI; v.z *= INV_2PI; v.w *= INV_2PI;
            lx4[r * 8 + (c4 ^ (r & 7))] = v;
        }
    };

    stage(0);

    for (int ic = 0; ic < 8; ++ic) {
        __syncthreads();

        // readback my b-row: 8 x ds_read_b128, bank-even via swizzle
        float xs[CH];
#pragma unroll
        for (int c4 = 0; c4 < 8; ++c4) {
            const float4 v = lx4[l * 8 + (c4 ^ (l & 7))];
            xs[c4 * 4 + 0] = v.x; xs[c4 * 4 + 1] = v.y;
            xs[c4 * 4 + 2] = v.z; xs[c4 * 4 + 3] = v.w;
        }

        __syncthreads();

        if (ic < 7) stage(ic + 1);   // overlap staging with compute

        const int ib = ic * CH;
#pragma unroll
        for (int j = 0; j < CH; ++j) {
            const float xv = xs[j];   // pre-scaled: w*xv is in revolutions

            // --- o0: transcendental pipe ---
            acc0 = fmaf(g0r[ib + j],
                        __builtin_amdgcn_sinf(w0r[ib + j] * xv), acc0);

            // --- o1: full-rate VALU polynomial ---
            {
                const float arg = w1r[ib + j] * xv;
                const float rnd = (arg + RND_MAGIC) - RND_MAGIC; // rne(arg)
                const float f   = arg - rnd;                     // [-0.5,0.5]
                const float u   = f * f;
                float p = C13;
                p = fmaf(p, u, C11); p = fmaf(p, u, C9);
                p = fmaf(p, u, C7);  p = fmaf(p, u, C5);
                p = fmaf(p, u, C3);  p = fmaf(p, u, C1);
                acc1 = fmaf(f * g1r[ib + j], p, acc1);           // g*f*P
            }
        }
    }

    y[(b0 + l) * OUT_DIM + o0] = acc0;
    y[(b0 + l) * OUT_DIM + o1] = acc1;
}

extern "C" void kernel_launch(void* const* d_in, const int* in_sizes, int n_in,
                              void* d_out, int out_size, void* d_ws, size_t ws_size,
                              hipStream_t stream) {
    const float* x      = (const float*)d_in[0];
    const float* weight = (const float*)d_in[1];
    const float* wfreq  = (const float*)d_in[2];
    float* y            = (float*)d_out;

    const int B = in_sizes[0] / IN_DIM;            // 2048
    const int grid = (B / 64) * (OUT_DIM / 8);     // 32 * 32 = 1024

    skan_kernel<<<grid, 256, 0, stream>>>(x, weight, wfreq, y);
}